// Round 13
// baseline (140.731 us; speedup 1.0000x reference)
//
#include <hip/hip_runtime.h>
#include <hip/hip_bf16.h>

#define N_ATOMS 512
#define CDIM 64
#define NSIG 16384
#define KS 4
#define NBINS 33
#define NS_BLK 16   // signals per block: 4 waves x 4 signal-groups (16 lanes each)

// ws layout (floats): [0,32768) Dn[c][n] ; [32768,65536) DnT[n][c] ;
// [65536,327680) G[n][n] ; [327680,344064) per-signal loss partials
#define WS_DN   0
#define WS_DNT  32768
#define WS_G    65536
#define WS_PART 327680

// LDS column swizzle for Hs: col = n ^ ((n>>5)&7)<<2 == n ^ ((n>>3)&28).
// Self-inverse; breaks the 16-way bank conflict of 32-atom-per-lane slices.
__device__ __forceinline__ int swz(int n) { return n ^ ((n >> 3) & 28); }

__global__ void k_normalize(const float* __restrict__ dict,
                            float* __restrict__ Dn, float* __restrict__ DnT) {
    const int n = blockIdx.x;    // atom/column
    const int c = threadIdx.x;   // channel/row (64 threads = 1 wave)
    float v = dict[c * N_ATOMS + n];
    float sq = v * v;
    #pragma unroll
    for (int off = 32; off > 0; off >>= 1) sq += __shfl_down(sq, off);
    sq = __shfl(sq, 0);
    float m = fmaxf(sqrtf(sq), 1e-10f);
    float r = v / m;             // division to match reference exactly
    Dn[c * N_ATOMS + n] = r;
    DnT[n * CDIM + c]  = r;
}

__global__ void k_gram(const float* __restrict__ Dn, float* __restrict__ G) {
    __shared__ float sc[CDIM];
    const int i = blockIdx.x;
    const int t = threadIdx.x;
    if (t < CDIM) sc[t] = Dn[t * N_ATOMS + i];
    __syncthreads();
    for (int j = t; j < N_ATOMS; j += 256) {
        float a = 0.f;
        #pragma unroll
        for (int c = 0; c < CDIM; c++) a = fmaf(sc[c], Dn[c * N_ATOMS + j], a);
        G[i * N_ATOMS + j] = a;
    }
}

// Fused v5: GEMM -> swizzled LDS h_bar -> 16-lane-group OMP (4 signals/wave
// in parallel) -> wave-per-signal epilogue.
__global__ __launch_bounds__(256, 4) void k_fused4(
    const float* __restrict__ z, const float* __restrict__ Dn,
    const float* __restrict__ DnT, const float* __restrict__ G,
    float* __restrict__ part, float* __restrict__ out)
{
    __shared__ float Xs[CDIM][20];     // [c][s] 16 signals + pad->20 (rows 16B-aligned)
    __shared__ float Hs[NS_BLK][516];  // swizzled hbar; later zste overlay (cols 0..63)
    __shared__ float cqA[NS_BLK][4];
    __shared__ int   IA[NS_BLK][4];
    __shared__ float tkA[NS_BLK][4];
    const int t = threadIdx.x;
    const int wave = t >> 6, lane = t & 63;
    const int s0 = blockIdx.x * NS_BLK;
    const int b = s0 >> 10;
    const int hw0 = s0 & 1023;

    {   // coalesced z stage: thread t -> channel c = t>>2, signals f..f+3
        const int c = t >> 2, f = (t & 3) * 4;
        float4 v = *(const float4*)(z + (b * CDIM + c) * 1024 + hw0 + f);
        *(float4*)(&Xs[c][f]) = v;
    }
    __syncthreads();

    {   // GEMM: wave owns atoms [wave*128,+128), lane owns 2; 16 signals.
        // k-ascending fmaf per (signal, atom) — bit-identical to prior rounds.
        const int n0 = wave * 128 + lane * 2;
        const int col0 = swz(n0);          // n0 even, swizzle keeps pair contiguous
        float acc[NS_BLK][2];
        #pragma unroll
        for (int q = 0; q < NS_BLK; q++) { acc[q][0] = 0.f; acc[q][1] = 0.f; }
        for (int k = 0; k < CDIM; k++) {
            const float2 d = *(const float2*)(Dn + k * N_ATOMS + n0);
            const float4 x0 = *(const float4*)(&Xs[k][0]);
            const float4 x1 = *(const float4*)(&Xs[k][4]);
            const float4 x2 = *(const float4*)(&Xs[k][8]);
            const float4 x3 = *(const float4*)(&Xs[k][12]);
            const float xs[16] = {x0.x, x0.y, x0.z, x0.w, x1.x, x1.y, x1.z, x1.w,
                                  x2.x, x2.y, x2.z, x2.w, x3.x, x3.y, x3.z, x3.w};
            #pragma unroll
            for (int q = 0; q < NS_BLK; q++) {
                acc[q][0] = fmaf(xs[q], d.x, acc[q][0]);
                acc[q][1] = fmaf(xs[q], d.y, acc[q][1]);
            }
        }
        #pragma unroll
        for (int q = 0; q < NS_BLK; q++)
            *(float2*)(&Hs[q][col0]) = make_float2(acc[q][0], acc[q][1]);
    }
    __syncthreads();

    // ---- group OMP: group g = 16 lanes = 1 signal; lane owns 32 atoms ----
    const int g = lane >> 4, gl = lane & 15;
    const int sl = wave * 4 + g;
    const float* hrow = &Hs[sl][0];

    float ha[32];   // |h| with selected entries zeroed (sign of h never used)
    #pragma unroll
    for (int j4 = 0; j4 < 8; j4++) {
        const int n = gl * 32 + j4 * 4;
        float4 hv = *(const float4*)(hrow + swz(n));
        ha[j4 * 4 + 0] = fabsf(hv.x); ha[j4 * 4 + 1] = fabsf(hv.y);
        ha[j4 * 4 + 2] = fabsf(hv.z); ha[j4 * 4 + 3] = fabsf(hv.w);
    }

    unsigned sel = 0;
    int I[KS]; float coef[KS];
    float L[KS][KS]; float hsel[KS]; float inv[KS];
    L[0][0] = 1.f; inv[0] = 1.f;

    #pragma unroll
    for (int k = 0; k < KS; k++) {
        // max value over group's 512 |h| (selected are exact 0 — matches where())
        float m0 = fmaxf(fmaxf(fmaxf(ha[0], ha[1]), fmaxf(ha[2], ha[3])),
                         fmaxf(fmaxf(ha[4], ha[5]), fmaxf(ha[6], ha[7])));
        float m1 = fmaxf(fmaxf(fmaxf(ha[8], ha[9]), fmaxf(ha[10], ha[11])),
                         fmaxf(fmaxf(ha[12], ha[13]), fmaxf(ha[14], ha[15])));
        float m2 = fmaxf(fmaxf(fmaxf(ha[16], ha[17]), fmaxf(ha[18], ha[19])),
                         fmaxf(fmaxf(ha[20], ha[21]), fmaxf(ha[22], ha[23])));
        float m3 = fmaxf(fmaxf(fmaxf(ha[24], ha[25]), fmaxf(ha[26], ha[27])),
                         fmaxf(fmaxf(ha[28], ha[29]), fmaxf(ha[30], ha[31])));
        float mv = fmaxf(fmaxf(m0, m1), fmaxf(m2, m3));
        #pragma unroll
        for (int off = 1; off <= 8; off <<= 1)      // 16-lane butterfly
            mv = fmaxf(mv, __shfl_xor(mv, off));
        // lowest atom index attaining mv (exact equality == first-max tie-break)
        int cand = 2048;
        #pragma unroll
        for (int j = 31; j >= 0; j--)
            if (ha[j] == mv) cand = gl * 32 + j;
        unsigned long long mk = __ballot(cand < 2048);
        const int lo = (int)__builtin_ctzll((mk >> (g * 16)) & 0xFFFFull);
        const int idx = __shfl(cand, g * 16 + lo);
        if ((idx >> 5) == gl) sel |= 1u << (idx & 31);

        if (k > 0) {
            float w[KS - 1];
            for (int i2 = 0; i2 < k; i2++) {
                float tt = G[I[i2] * N_ATOMS + idx];
                for (int j2 = 0; j2 < i2; j2++) tt -= L[i2][j2] * w[j2];
                w[i2] = tt * inv[i2];
            }
            float ssum = 0.f;
            for (int j2 = 0; j2 < k; j2++) ssum += w[j2] * w[j2];
            float corner = sqrtf(fmaxf(1.f - ssum, 1e-12f));
            for (int j2 = 0; j2 < k; j2++) L[k][j2] = w[j2];
            L[k][k] = corner;
            inv[k] = 1.f / corner;
        }
        I[k] = idx;
        hsel[k] = hrow[swz(idx)];     // h_bar[idx], same bits

        float y[KS];
        for (int i2 = 0; i2 <= k; i2++) {
            float tt = hsel[i2];
            for (int j2 = 0; j2 < i2; j2++) tt -= L[i2][j2] * y[j2];
            y[i2] = tt * inv[i2];
        }
        for (int i2 = k; i2 >= 0; i2--) {
            float tt = y[i2];
            for (int j2 = i2 + 1; j2 <= k; j2++) tt -= L[j2][i2] * coef[j2];
            coef[i2] = tt * inv[i2];
        }

        // h = h_bar - x @ G  (lane's 32 atoms; m-ascending fmaf as before)
        if (k < KS - 1) {
            float a[32];
            #pragma unroll
            for (int j = 0; j < 32; j++) a[j] = 0.f;
            for (int m = 0; m <= k; m++) {
                const float4* gr = (const float4*)(G + I[m] * N_ATOMS + gl * 32);
                const float cm = coef[m];
                #pragma unroll
                for (int j4 = 0; j4 < 8; j4++) {
                    float4 gv = gr[j4];
                    a[j4 * 4 + 0] = fmaf(cm, gv.x, a[j4 * 4 + 0]);
                    a[j4 * 4 + 1] = fmaf(cm, gv.y, a[j4 * 4 + 1]);
                    a[j4 * 4 + 2] = fmaf(cm, gv.z, a[j4 * 4 + 2]);
                    a[j4 * 4 + 3] = fmaf(cm, gv.w, a[j4 * 4 + 3]);
                }
            }
            #pragma unroll
            for (int j4 = 0; j4 < 8; j4++) {
                const int n = gl * 32 + j4 * 4;
                float4 hbv = *(const float4*)(hrow + swz(n));
                ha[j4 * 4 + 0] = ((sel >> (j4 * 4 + 0)) & 1) ? 0.f : fabsf(hbv.x - a[j4 * 4 + 0]);
                ha[j4 * 4 + 1] = ((sel >> (j4 * 4 + 1)) & 1) ? 0.f : fabsf(hbv.y - a[j4 * 4 + 1]);
                ha[j4 * 4 + 2] = ((sel >> (j4 * 4 + 2)) & 1) ? 0.f : fabsf(hbv.z - a[j4 * 4 + 2]);
                ha[j4 * 4 + 3] = ((sel >> (j4 * 4 + 3)) & 1) ? 0.f : fabsf(hbv.w - a[j4 * 4 + 3]);
            }
        }
    }

    if (gl == 0) {   // one lane per group: quantize + publish
        #pragma unroll
        for (int j = 0; j < KS; j++) {
            float c2 = fminf(fmaxf(coef[j], -2.f), 2.f);
            float bf = (c2 + 2.f) / 4.f * 32.f;
            int bin = (int)rintf(bf);
            bin = bin < 0 ? 0 : (bin > 32 ? 32 : bin);
            cqA[sl][j] = -2.f + 0.125f * (float)bin;
            IA[sl][j]  = I[j];
            tkA[sl][j] = (float)(I[j] * NBINS + bin);
        }
    }
    __syncthreads();

    // ---- epilogue: wave = 1 signal (64 channels), 4 rounds ----
    #pragma unroll
    for (int r = 0; r < 4; r++) {
        const int sl2 = r * 4 + wave;
        const int s = s0 + sl2;
        const float xch = Xs[lane][sl2];
        float zq = 0.f;
        #pragma unroll
        for (int j = 0; j < KS; j++)
            zq = fmaf(cqA[sl2][j], DnT[IA[sl2][j] * CDIM + lane], zq);
        float diff = zq - xch;
        Hs[sl2][lane] = xch + (zq - xch);   // zste overlay (Hs dead)
        float sq = diff * diff;
        #pragma unroll
        for (int off = 32; off > 0; off >>= 1) sq += __shfl_down(sq, off);
        if (lane == 0) part[s] = sq;
    }
    __syncthreads();

    {   // coalesced zste write
        const int c = t >> 2, f = (t & 3) * 4;
        float4 v;
        v.x = Hs[f + 0][c]; v.y = Hs[f + 1][c];
        v.z = Hs[f + 2][c]; v.w = Hs[f + 3][c];
        *(float4*)(out + (b * CDIM + c) * 1024 + hw0 + f) = v;
    }
    if (t < NS_BLK * KS)   // 64 consecutive token floats
        out[NSIG * CDIM + 1 + s0 * KS + t] = tkA[t >> 2][t & 3];
}

__global__ __launch_bounds__(256) void k_final(const float* __restrict__ part,
                                               float* __restrict__ out) {
    __shared__ float red[4];
    const int t = threadIdx.x;
    float sum = 0.f;
    const float4* p4 = (const float4*)part;
    for (int i = t; i < NSIG / 4; i += 256) {
        float4 v = p4[i];
        sum += v.x + v.y + v.z + v.w;
    }
    #pragma unroll
    for (int off = 32; off > 0; off >>= 1) sum += __shfl_down(sum, off);
    if ((t & 63) == 0) red[t >> 6] = sum;
    __syncthreads();
    if (t == 0) {
        float v = (red[0] + red[1] + red[2] + red[3]) / 1048576.f;
        out[NSIG * CDIM] = v + 0.25f * v;
    }
}

extern "C" void kernel_launch(void* const* d_in, const int* in_sizes, int n_in,
                              void* d_out, int out_size, void* d_ws, size_t ws_size,
                              hipStream_t stream) {
    const float* z    = (const float*)d_in[0];
    const float* dict = (const float*)d_in[1];
    float* out  = (float*)d_out;
    float* w    = (float*)d_ws;
    float* Dn   = w + WS_DN;
    float* DnT  = w + WS_DNT;
    float* G    = w + WS_G;
    float* part = w + WS_PART;

    hipLaunchKernelGGL(k_normalize, dim3(N_ATOMS), dim3(CDIM), 0, stream, dict, Dn, DnT);
    hipLaunchKernelGGL(k_gram,      dim3(N_ATOMS), dim3(256),  0, stream, Dn, G);
    hipLaunchKernelGGL(k_fused4,    dim3(NSIG / NS_BLK), dim3(256), 0, stream,
                       z, Dn, DnT, G, part, out);
    hipLaunchKernelGGL(k_final,     dim3(1), dim3(256), 0, stream, part, out);
}